// Round 14
// baseline (100.247 us; speedup 1.0000x reference)
//
#include <hip/hip_runtime.h>
#include <math.h>

// LNCC as 3 streaming kernels + fused finalize (R12 lesson: LDS-fused
// variants run at 25-35% of achievable BW; pure streaming at ~60-70%):
//  K1 W-pass: thread owns 8 w, loads only its own 8 cols (2xfloat4);
//     +-4-col halo via __shfl; w-edge lanes reflect in-register.
//     5-ch register slide, u16 quant x(65535/9), uint4 store. Also zeroes
//     the K3 completion counter (stream-ordered before K3).
//  K2 H-pass: thread owns 8h x 4w; 16 uint2 loads/ch; INTEGER sliding
//     (exact); requantize /9 to u16. Channel loop rolled (~80 VGPR).
//  K3 D-pass+LNCC+finalize: integer-exact D slide on u16, LNCC, block
//     reduce; completion-counter pattern — last block double-reduces the
//     2048 partials in fixed order (deterministic) -> d_out[0] = -mean.
// Quantization chain: Wq = round(Wsum*65535/9)  (Wsum <= 9)
//                     WHq = round(sum9(Wq)/9) ~= WHsum*65535/81 (<= 65535)
//                     Sd  = sum9(WHq) < 2^24 (exact in fp32)
//                     E[.] = Sd * 81/65535/729 = DQ3 (R10 bug: 9/.. = 9x off)

#define NVOX 4194304        // 2*128*128*128
#define SLICE 16384         // 128*128
#define S1 (65535.0f / 9.0f)
#define DQ3 ((float)(81.0 / 65535.0 / 729.0))
#define NBLK3 2048

__device__ __forceinline__ int refl(int p) {
    // reflect (no edge repeat) for dim 128
    return 127 - abs(abs(p) - 127);
}

__global__ __launch_bounds__(256)
void lncc_w_kernel(const float* __restrict__ f, const float* __restrict__ w,
                   unsigned short* __restrict__ wq,
                   unsigned int* __restrict__ counter) {
    if (blockIdx.x == 0 && threadIdx.x == 0) *counter = 0u;

    // 524288 threads: thread -> (row = b*128*128 + d*128 + h, w-octet)
    const int gtid = blockIdx.x * 256 + threadIdx.x;
    const int wo  = gtid & 15;
    const int row = gtid >> 4;
    const int w0  = wo << 3;

    const float* fr = f + (size_t)row * 128 + w0;
    const float* wr = w + (size_t)row * 128 + w0;
    float Lf[8], Lw[8];
    *(float4*)&Lf[0] = *(const float4*)&fr[0];
    *(float4*)&Lf[4] = *(const float4*)&fr[4];
    *(float4*)&Lw[0] = *(const float4*)&wr[0];
    *(float4*)&Lw[4] = *(const float4*)&wr[4];

    // window cols w0-4 .. w0+11: fv[4..11] own, halo via neighbor-lane shfl
    float fv[16], wv[16];
#pragma unroll
    for (int t = 0; t < 8; ++t) { fv[4 + t] = Lf[t]; wv[4 + t] = Lw[t]; }
#pragma unroll
    for (int t = 0; t < 4; ++t) {          // left halo = lane-1's L[4..7]
        fv[t] = __shfl_up(Lf[4 + t], 1, 64);
        wv[t] = __shfl_up(Lw[4 + t], 1, 64);
    }
#pragma unroll
    for (int t = 0; t < 4; ++t) {          // right halo = lane+1's L[0..3]
        fv[12 + t] = __shfl_down(Lf[t], 1, 64);
        wv[12 + t] = __shfl_down(Lw[t], 1, 64);
    }
    if (wo == 0) {    // cols -4..-1 -> refl 4,3,2,1 (own registers)
        fv[0] = Lf[4]; fv[1] = Lf[3]; fv[2] = Lf[2]; fv[3] = Lf[1];
        wv[0] = Lw[4]; wv[1] = Lw[3]; wv[2] = Lw[2]; wv[3] = Lw[1];
    }
    if (wo == 15) {   // cols 128..131 -> refl 126..123 = L[6],L[5],L[4],L[3]
        fv[12] = Lf[6]; fv[13] = Lf[5]; fv[14] = Lf[4]; fv[15] = Lf[3];
        wv[12] = Lw[6]; wv[13] = Lw[5]; wv[14] = Lw[4]; wv[15] = Lw[3];
    }

    unsigned int q[5][8];
    float sf = 0.f, sw = 0.f, sff = 0.f, sww = 0.f, sfw = 0.f;
#pragma unroll
    for (int t = 0; t < 9; ++t) {
        sf += fv[t]; sw += wv[t];
        sff = fmaf(fv[t], fv[t], sff);
        sww = fmaf(wv[t], wv[t], sww);
        sfw = fmaf(fv[t], wv[t], sfw);
    }
    q[0][0] = (unsigned short)fmaf(sf,  S1, 0.5f);
    q[1][0] = (unsigned short)fmaf(sw,  S1, 0.5f);
    q[2][0] = (unsigned short)fmaf(sff, S1, 0.5f);
    q[3][0] = (unsigned short)fmaf(sww, S1, 0.5f);
    q[4][0] = (unsigned short)fmaf(sfw, S1, 0.5f);
#pragma unroll
    for (int k = 1; k < 8; ++k) {
        float fe = fv[k + 8], fx = fv[k - 1];
        float we = wv[k + 8], wx = wv[k - 1];
        sf += fe - fx; sw += we - wx;
        sff = fmaf(fe, fe, sff); sff = fmaf(-fx, fx, sff);
        sww = fmaf(we, we, sww); sww = fmaf(-wx, wx, sww);
        sfw = fmaf(fe, we, sfw); sfw = fmaf(-fx, wx, sfw);
        q[0][k] = (unsigned short)fmaf(sf,  S1, 0.5f);
        q[1][k] = (unsigned short)fmaf(sw,  S1, 0.5f);
        q[2][k] = (unsigned short)fmaf(sff, S1, 0.5f);
        q[3][k] = (unsigned short)fmaf(sww, S1, 0.5f);
        q[4][k] = (unsigned short)fmaf(sfw, S1, 0.5f);
    }
#pragma unroll
    for (int c = 0; c < 5; ++c) {
        uint4 P;
        P.x = q[c][0] | (q[c][1] << 16);
        P.y = q[c][2] | (q[c][3] << 16);
        P.z = q[c][4] | (q[c][5] << 16);
        P.w = q[c][6] | (q[c][7] << 16);
        *(uint4*)&wq[(size_t)c * NVOX + (size_t)row * 128 + w0] = P;
    }
}

__global__ __launch_bounds__(256)
void lncc_h_kernel(const unsigned short* __restrict__ wq,
                   unsigned short* __restrict__ whq) {
    // 131072 threads (512 blocks): thread -> (bd, h-octet, w-quad)
    const int gtid = blockIdx.x * 256 + threadIdx.x;
    const int wq4 = gtid & 31;              // w0 = 4*wq4
    const int ho  = (gtid >> 5) & 15;
    const int bd  = gtid >> 9;              // b*128 + d
    const int h0  = ho << 3;

#pragma unroll 1                            // keep channels rolled
    for (int c = 0; c < 5; ++c) {
        const unsigned short* base = wq + (size_t)c * NVOX + (size_t)bd * SLICE;
        unsigned short* ob = whq + (size_t)c * NVOX + (size_t)bd * SLICE;
        unsigned int v0[16], v1[16], v2[16], v3[16];
#pragma unroll
        for (int r = 0; r < 16; ++r) {
            int hh = refl(h0 - 4 + r);
            uint2 pr = *(const uint2*)&base[(size_t)hh * 128 + 4 * wq4];
            v0[r] = pr.x & 0xffffu;  v1[r] = pr.x >> 16;
            v2[r] = pr.y & 0xffffu;  v3[r] = pr.y >> 16;
        }
        unsigned int s0 = 0, s1 = 0, s2 = 0, s3 = 0;
#pragma unroll
        for (int r = 0; r < 9; ++r) { s0 += v0[r]; s1 += v1[r]; s2 += v2[r]; s3 += v3[r]; }
#pragma unroll
        for (int k = 0; k < 8; ++k) {
            if (k > 0) {
                s0 += v0[k + 8] - v0[k - 1]; s1 += v1[k + 8] - v1[k - 1];
                s2 += v2[k + 8] - v2[k - 1]; s3 += v3[k + 8] - v3[k - 1];
            }
            unsigned int a = (unsigned short)fmaf((float)s0, 1.0f / 9.0f, 0.5f);
            unsigned int b = (unsigned short)fmaf((float)s1, 1.0f / 9.0f, 0.5f);
            unsigned int cc = (unsigned short)fmaf((float)s2, 1.0f / 9.0f, 0.5f);
            unsigned int dd = (unsigned short)fmaf((float)s3, 1.0f / 9.0f, 0.5f);
            uint2 Q; Q.x = a | (b << 16); Q.y = cc | (dd << 16);
            *(uint2*)&ob[(size_t)(h0 + k) * 128 + 4 * wq4] = Q;
        }
    }
}

__global__ __launch_bounds__(256)
void lncc_d_kernel(const unsigned short* __restrict__ buf,
                   float* __restrict__ partials,
                   unsigned int* __restrict__ counter,
                   float* __restrict__ out) {
    // 524288 threads: thread -> (b, dchunk(16), h, w), 8 d-outputs each
    const int gtid = blockIdx.x * 256 + threadIdx.x;
    const int wc = gtid & 127;
    const int h  = (gtid >> 7) & 127;
    const int dc = (gtid >> 14) & 15;
    const int b  = gtid >> 18;
    const int d0 = dc << 3;

    float s[5][8];
#pragma unroll
    for (int c = 0; c < 5; ++c) {
        const unsigned short* bc = buf + (size_t)c * NVOX
                                 + (size_t)b * (128 * SLICE)
                                 + (size_t)h * 128 + wc;
        float v[16];
#pragma unroll
        for (int t = 0; t < 16; ++t) {
            int d = refl(d0 - 4 + t);
            v[t] = (float)bc[(size_t)d * SLICE];
        }
        float acc = 0.f;
#pragma unroll
        for (int t = 0; t < 9; ++t) acc += v[t];
        s[c][0] = acc;
#pragma unroll
        for (int j = 1; j < 8; ++j) {
            acc += v[j + 8] - v[j - 1];
            s[c][j] = acc;
        }
    }

    float lsum = 0.f;
#pragma unroll
    for (int j = 0; j < 8; ++j) {
        float mf = s[0][j] * DQ3;
        float mw = s[1][j] * DQ3;
        float sgf = fmaxf(s[2][j] * DQ3 - mf * mf, 1e-8f);
        float sgw = fmaxf(s[3][j] * DQ3 - mw * mw, 1e-8f);
        float sfw = s[4][j] * DQ3 - mf * mw;
        float denom = fmaxf(sqrtf(fmaxf(sgf * sgw, 1e-16f)), 1e-8f);
        float l = sfw / denom;
        lsum += fminf(fmaxf(l, -10.f), 10.f);
    }

#pragma unroll
    for (int off = 32; off > 0; off >>= 1)
        lsum += __shfl_down(lsum, off, 64);
    __shared__ float red[4];
    __shared__ bool amLast;
    int lane = threadIdx.x & 63, wid = threadIdx.x >> 6;
    if (lane == 0) red[wid] = lsum;
    __syncthreads();
    if (threadIdx.x == 0) {
        partials[blockIdx.x] = red[0] + red[1] + red[2] + red[3];
        __threadfence();                       // make partial visible device-wide
        unsigned int old = atomicAdd(counter, 1u);
        amLast = (old == NBLK3 - 1);
    }
    __syncthreads();

    if (amLast) {                              // last block: fixed-order reduce
        __threadfence();                       // acquire: see all partials
        double acc = 0.0;
        for (int i = threadIdx.x; i < NBLK3; i += 256) acc += (double)partials[i];
        __shared__ double rd[256];
        rd[threadIdx.x] = acc;
        __syncthreads();
        for (int t = 128; t > 0; t >>= 1) {
            if (threadIdx.x < t) rd[threadIdx.x] += rd[threadIdx.x + t];
            __syncthreads();
        }
        if (threadIdx.x == 0) out[0] = (float)(-rd[0] / (double)NVOX);
    }
}

extern "C" void kernel_launch(void* const* d_in, const int* in_sizes, int n_in,
                              void* d_out, int out_size, void* d_ws, size_t ws_size,
                              hipStream_t stream) {
    const float* f = (const float*)d_in[0];
    const float* w = (const float*)d_in[1];
    float* out = (float*)d_out;

    unsigned short* wqb  = (unsigned short*)d_ws;                       // 40 MB
    unsigned short* whqb = wqb + (size_t)5 * NVOX;                      // 40 MB
    float* partials = (float*)((char*)d_ws + (size_t)20 * NVOX);        // 2048 f
    unsigned int* counter = (unsigned int*)(partials + NBLK3);

    lncc_w_kernel<<<2048, 256, 0, stream>>>(f, w, wqb, counter);
    lncc_h_kernel<<<512, 256, 0, stream>>>(wqb, whqb);
    lncc_d_kernel<<<NBLK3, 256, 0, stream>>>(whqb, partials, counter, out);
}

// Round 15
// 45.679 us; speedup vs baseline: 2.1946x; 2.1946x over previous
//
#include <hip/hip_runtime.h>
#include <math.h>

// LNCC as 4 streaming kernels, all kernel-B-style (no LDS, no barriers,
// 1-D register sliding, low VGPR, high occupancy).
// Hard-won lessons encoded here:
//  - R3-R9: any 2-D-halo-per-thread kernel is latency-bound (10-25% VALU).
//  - R12: LDS-fused W+H runs at 25-35% of achievable BW; split streaming ~70%.
//  - R5/R6: min-waves launch_bounds hints cap VGPR and spill the sliding
//    arrays (862/580 MB scratch). Plain __launch_bounds__(256) only.
//  - R14: fusing the final reduction into K3 (completion counter) made the
//    allocator drop K3 to 32 VGPR -> spilled streaming body, 6->68 us. Keep
//    the separate 1-block final kernel.
//  K1 W-pass: thread owns 8 w; 3x float4 overlapped loads (L2 absorbs the
//     2x sector overlap — removing it via shfl was neutral, R13);
//     5-ch register slide; u16 quant x(65535/9); uint4 store.
//  K2 H-pass: thread owns 8h x 2w; 16 b32 loads/ch; INTEGER sliding (exact);
//     requantize /9 to u16. Channel loop rolled to keep ~60 VGPR.
//  K3 D-pass+LNCC: integer-exact D slide on u16, LNCC, block reduce.
//  C  deterministic double reduction -> d_out[0] = -mean.
// Quantization chain: Wq = round(Wsum*65535/9)  (Wsum <= 9)
//                     WHq = round(sum9(Wq)/9) ~= WHsum*65535/81 (<= 65535)
//                     Sd  = sum9(WHq) < 2^24 (exact in fp32)
//                     E[.] = Sd * 81/65535/729 = DQ3 (R10 bug: 9/.. = 9x off)

#define NVOX 4194304        // 2*128*128*128
#define SLICE 16384         // 128*128
#define S1 (65535.0f / 9.0f)
#define DQ3 ((float)(81.0 / 65535.0 / 729.0))

__device__ __forceinline__ int refl(int p) {
    // reflect (no edge repeat) for dim 128
    return 127 - abs(abs(p) - 127);
}

__global__ __launch_bounds__(256)
void lncc_w_kernel(const float* __restrict__ f, const float* __restrict__ w,
                   unsigned short* __restrict__ wq) {
    // 524288 threads: thread -> (row = b*128*128 + d*128 + h, w-octet)
    const int gtid = blockIdx.x * 256 + threadIdx.x;
    const int wo  = gtid & 15;
    const int row = gtid >> 4;
    const int w0  = wo << 3;
    const int edge = (wo == 0) ? 1 : ((wo == 15) ? 2 : 0);
    const int jbc  = (edge == 1) ? 0 : ((edge == 2) ? 112 : (w0 - 4));

    const float* fr = f + (size_t)row * 128 + jbc;
    const float* wr = w + (size_t)row * 128 + jbc;
    float Lf[16], Lw[16];
#pragma unroll
    for (int t = 0; t < 4; ++t) {
        *(float4*)&Lf[4 * t] = *(const float4*)&fr[4 * t];
        *(float4*)&Lw[4 * t] = *(const float4*)&wr[4 * t];
    }
    // window cols w0-4 .. w0+11 (16 wide for 8 outputs), reflected at edges
    float fv[16], wv[16];
    if (edge == 1) {
        const int pm[16] = {4,3,2,1,0,1,2,3,4,5,6,7,8,9,10,11};
#pragma unroll
        for (int t = 0; t < 16; ++t) { fv[t] = Lf[pm[t]]; wv[t] = Lw[pm[t]]; }
    } else if (edge == 2) {
        const int pm[16] = {4,5,6,7,8,9,10,11,12,13,14,15,14,13,12,11};
#pragma unroll
        for (int t = 0; t < 16; ++t) { fv[t] = Lf[pm[t]]; wv[t] = Lw[pm[t]]; }
    } else {
#pragma unroll
        for (int t = 0; t < 16; ++t) { fv[t] = Lf[t]; wv[t] = Lw[t]; }
    }

    unsigned int q[5][8];
    float sf = 0.f, sw = 0.f, sff = 0.f, sww = 0.f, sfw = 0.f;
#pragma unroll
    for (int t = 0; t < 9; ++t) {
        sf += fv[t]; sw += wv[t];
        sff = fmaf(fv[t], fv[t], sff);
        sww = fmaf(wv[t], wv[t], sww);
        sfw = fmaf(fv[t], wv[t], sfw);
    }
    q[0][0] = (unsigned short)fmaf(sf,  S1, 0.5f);
    q[1][0] = (unsigned short)fmaf(sw,  S1, 0.5f);
    q[2][0] = (unsigned short)fmaf(sff, S1, 0.5f);
    q[3][0] = (unsigned short)fmaf(sww, S1, 0.5f);
    q[4][0] = (unsigned short)fmaf(sfw, S1, 0.5f);
#pragma unroll
    for (int k = 1; k < 8; ++k) {
        float fe = fv[k + 8], fx = fv[k - 1];
        float we = wv[k + 8], wx = wv[k - 1];
        sf += fe - fx; sw += we - wx;
        sff = fmaf(fe, fe, sff); sff = fmaf(-fx, fx, sff);
        sww = fmaf(we, we, sww); sww = fmaf(-wx, wx, sww);
        sfw = fmaf(fe, we, sfw); sfw = fmaf(-fx, wx, sfw);
        q[0][k] = (unsigned short)fmaf(sf,  S1, 0.5f);
        q[1][k] = (unsigned short)fmaf(sw,  S1, 0.5f);
        q[2][k] = (unsigned short)fmaf(sff, S1, 0.5f);
        q[3][k] = (unsigned short)fmaf(sww, S1, 0.5f);
        q[4][k] = (unsigned short)fmaf(sfw, S1, 0.5f);
    }
#pragma unroll
    for (int c = 0; c < 5; ++c) {
        uint4 P;
        P.x = q[c][0] | (q[c][1] << 16);
        P.y = q[c][2] | (q[c][3] << 16);
        P.z = q[c][4] | (q[c][5] << 16);
        P.w = q[c][6] | (q[c][7] << 16);
        *(uint4*)&wq[(size_t)c * NVOX + (size_t)row * 128 + w0] = P;
    }
}

__global__ __launch_bounds__(256)
void lncc_h_kernel(const unsigned short* __restrict__ wq,
                   unsigned short* __restrict__ whq) {
    // 262144 threads: thread -> (bd, h-octet, w-pair); integer sliding sums
    const int gtid = blockIdx.x * 256 + threadIdx.x;
    const int wp = gtid & 63;
    const int ho = (gtid >> 6) & 15;
    const int bd = gtid >> 10;              // b*128 + d
    const int h0 = ho << 3;

#pragma unroll 1                            // keep channels rolled: ~60 VGPR
    for (int c = 0; c < 5; ++c) {
        const unsigned short* base = wq + (size_t)c * NVOX + (size_t)bd * SLICE;
        unsigned short* ob = whq + (size_t)c * NVOX + (size_t)bd * SLICE;
        unsigned int v0[16], v1[16];
#pragma unroll
        for (int r = 0; r < 16; ++r) {
            int hh = refl(h0 - 4 + r);
            unsigned int pr = *(const unsigned int*)&base[(size_t)hh * 128 + 2 * wp];
            v0[r] = pr & 0xffffu;
            v1[r] = pr >> 16;
        }
        unsigned int s0 = 0, s1 = 0;
#pragma unroll
        for (int r = 0; r < 9; ++r) { s0 += v0[r]; s1 += v1[r]; }
#pragma unroll
        for (int k = 0; k < 8; ++k) {
            if (k > 0) { s0 += v0[k + 8] - v0[k - 1]; s1 += v1[k + 8] - v1[k - 1]; }
            unsigned int a = (unsigned short)fmaf((float)s0, 1.0f / 9.0f, 0.5f);
            unsigned int b = (unsigned short)fmaf((float)s1, 1.0f / 9.0f, 0.5f);
            *(unsigned int*)&ob[(size_t)(h0 + k) * 128 + 2 * wp] = a | (b << 16);
        }
    }
}

__global__ __launch_bounds__(256)
void lncc_d_kernel(const unsigned short* __restrict__ buf,
                   float* __restrict__ partials) {
    // 524288 threads: thread -> (b, dchunk(16), h, w), 8 d-outputs each
    const int gtid = blockIdx.x * 256 + threadIdx.x;
    const int wc = gtid & 127;
    const int h  = (gtid >> 7) & 127;
    const int dc = (gtid >> 14) & 15;
    const int b  = gtid >> 18;
    const int d0 = dc << 3;

    float s[5][8];
#pragma unroll
    for (int c = 0; c < 5; ++c) {
        const unsigned short* bc = buf + (size_t)c * NVOX
                                 + (size_t)b * (128 * SLICE)
                                 + (size_t)h * 128 + wc;
        float v[16];
#pragma unroll
        for (int t = 0; t < 16; ++t) {
            int d = refl(d0 - 4 + t);
            v[t] = (float)bc[(size_t)d * SLICE];
        }
        float acc = 0.f;
#pragma unroll
        for (int t = 0; t < 9; ++t) acc += v[t];
        s[c][0] = acc;
#pragma unroll
        for (int j = 1; j < 8; ++j) {
            acc += v[j + 8] - v[j - 1];
            s[c][j] = acc;
        }
    }

    float lsum = 0.f;
#pragma unroll
    for (int j = 0; j < 8; ++j) {
        float mf = s[0][j] * DQ3;
        float mw = s[1][j] * DQ3;
        float sgf = fmaxf(s[2][j] * DQ3 - mf * mf, 1e-8f);
        float sgw = fmaxf(s[3][j] * DQ3 - mw * mw, 1e-8f);
        float sfw = s[4][j] * DQ3 - mf * mw;
        float denom = fmaxf(sqrtf(fmaxf(sgf * sgw, 1e-16f)), 1e-8f);
        float l = sfw / denom;
        lsum += fminf(fmaxf(l, -10.f), 10.f);
    }

#pragma unroll
    for (int off = 32; off > 0; off >>= 1)
        lsum += __shfl_down(lsum, off, 64);
    __shared__ float red[4];
    int lane = threadIdx.x & 63, wid = threadIdx.x >> 6;
    if (lane == 0) red[wid] = lsum;
    __syncthreads();
    if (threadIdx.x == 0)
        partials[blockIdx.x] = red[0] + red[1] + red[2] + red[3];
}

__global__ __launch_bounds__(256)
void lncc_final_kernel(const float* __restrict__ partials, int n,
                       float* __restrict__ out) {
    __shared__ double rd[256];
    double acc = 0.0;
    for (int i = threadIdx.x; i < n; i += 256) acc += (double)partials[i];
    rd[threadIdx.x] = acc;
    __syncthreads();
    for (int s = 128; s > 0; s >>= 1) {
        if (threadIdx.x < s) rd[threadIdx.x] += rd[threadIdx.x + s];
        __syncthreads();
    }
    if (threadIdx.x == 0) out[0] = (float)(-rd[0] / (double)NVOX);
}

extern "C" void kernel_launch(void* const* d_in, const int* in_sizes, int n_in,
                              void* d_out, int out_size, void* d_ws, size_t ws_size,
                              hipStream_t stream) {
    const float* f = (const float*)d_in[0];
    const float* w = (const float*)d_in[1];
    float* out = (float*)d_out;

    unsigned short* wqb  = (unsigned short*)d_ws;                       // 40 MB
    unsigned short* whqb = wqb + (size_t)5 * NVOX;                      // 40 MB
    float* partials = (float*)((char*)d_ws + (size_t)20 * NVOX);        // 2048 f

    lncc_w_kernel<<<2048, 256, 0, stream>>>(f, w, wqb);
    lncc_h_kernel<<<1024, 256, 0, stream>>>(wqb, whqb);
    lncc_d_kernel<<<2048, 256, 0, stream>>>(whqb, partials);
    lncc_final_kernel<<<1, 256, 0, stream>>>(partials, 2048, out);
}